// Round 12
// baseline (1033.603 us; speedup 1.0000x reference)
//
#include <hip/hip_runtime.h>
#include <hip/hip_bf16.h>

constexpr int TT = 4096;   // tokens
constexpr int HH = 2048;   // hidden
constexpr int II = 2048;   // intermediate
constexpr int EE = 16;     // experts
constexpr int KTOP = 4;    // top-k

typedef __attribute__((ext_vector_type(4))) float f4;
typedef __attribute__((ext_vector_type(8))) short s8;

__device__ __forceinline__ short f2bf(float f) {
    union { __hip_bfloat16 b; short s; } u;
    u.b = __float2bfloat16(f);
    return u.s;
}
__device__ __forceinline__ float bf2f(short s) {
    union { unsigned u; float f; } v;
    v.u = ((unsigned)(unsigned short)s) << 16;
    return v.f;
}

// async global->LDS, 16B/lane. LDS dest: wave-uniform base (+lane*16 by HW);
// global source per-lane (gather + swizzle capable).
__device__ __forceinline__ void g2l16(const void* g, void* l) {
    __builtin_amdgcn_global_load_lds(
        (const __attribute__((address_space(1))) void*)g,
        (__attribute__((address_space(3))) void*)l, 16, 0, 0);
}

// ---------------------------------------------------------------------------
// Router + RMSNorm fused: t = rmsnorm(x)*gamma -> t16; top-4 route lists.
// ---------------------------------------------------------------------------
__global__ void k_router(const float* __restrict__ x, const float* __restrict__ gamma,
                         const float* __restrict__ wg, const float* __restrict__ bg,
                         short* __restrict__ t16, int* __restrict__ cnt,
                         int* __restrict__ lst, float* __restrict__ lwt) {
    const int lane = threadIdx.x & 63;
    const int tok = blockIdx.x * 4 + (threadIdx.x >> 6);
    const float* xr = x + (size_t)tok * HH;
    float t[32];
    float ss = 0.f;
#pragma unroll
    for (int j = 0; j < 32; j++) { float v = xr[lane + 64 * j]; t[j] = v; ss += v * v; }
#pragma unroll
    for (int m = 32; m >= 1; m >>= 1) ss += __shfl_xor(ss, m);
    const float rs = rsqrtf(ss * (1.f / HH) + 1e-6f);
#pragma unroll
    for (int j = 0; j < 32; j++) t[j] *= rs * gamma[lane + 64 * j];

    short* tr = t16 + (size_t)tok * HH;
#pragma unroll
    for (int j = 0; j < 32; j++) tr[lane + 64 * j] = f2bf(t[j]);

    float logit[EE];
#pragma unroll
    for (int e = 0; e < EE; e++) {
        const float* wrow = wg + (size_t)e * HH;
        float a = 0.f;
#pragma unroll
        for (int j = 0; j < 32; j++) a += t[j] * wrow[lane + 64 * j];
#pragma unroll
        for (int m = 32; m >= 1; m >>= 1) a += __shfl_xor(a, m);
        logit[e] = a + bg[e];
    }
    unsigned chosen = 0u;
    int sel[KTOP]; float sv[KTOP];
#pragma unroll
    for (int k = 0; k < KTOP; k++) {
        float best = -1e30f; int bi = 0;
#pragma unroll
        for (int e = 0; e < EE; e++) {
            bool take = (!((chosen >> e) & 1u)) && (logit[e] > best);
            if (take) { best = logit[e]; bi = e; }
        }
        chosen |= 1u << bi; sel[k] = bi; sv[k] = best;
    }
    const float lmax = sv[0];
    float s = 0.f;
#pragma unroll
    for (int k = 0; k < KTOP; k++) { sv[k] = expf(sv[k] - lmax); s += sv[k]; }
    const float inv = 1.f / s;
    if (lane == 0) {
#pragma unroll
        for (int k = 0; k < KTOP; k++) {
            int e = sel[k];
            int p = atomicAdd(&cnt[e], 1);
            lst[e * TT + p] = tok * KTOP + k;
            lwt[e * TT + p] = sv[k] * inv;
        }
    }
}

// ---------------------------------------------------------------------------
// FUSED gate+up GEMM, all-DMA ping-pong pipeline.
// Tile 128(m) x 64(n), BK=32, 4 waves (2x2; wave tile 64x32).
// LDS: A bf16 [2][128x32] + B1,B2 fp32 [2][64x32] = 48.5K -> 3 blocks/CU.
// All staging via global_load_lds, pre-swizzled sources (XOR slot^(row&mask)),
// fp32->bf16 cvt at ds_read. Pipeline: issue DMA(kt+1) -> vmcnt(6) waits
// DMA(kt) (full-iter flight) -> barrier -> read/cvt/MFMA -> barrier (WAR).
// ---------------------------------------------------------------------------
__global__ __launch_bounds__(256, 3) void k_ffn(
        const short* __restrict__ t16, const float* __restrict__ w1,
        const float* __restrict__ w3, short* __restrict__ h,
        const int* __restrict__ cnt, const int* __restrict__ lst) {
    const int e = blockIdx.z;
    const int Me = cnt[e];
    const int m0 = blockIdx.y * 128;
    if (m0 >= Me) return;
    const int n0 = blockIdx.x * 64;
    const float* we1 = w1 + (size_t)e * II * HH;
    const float* we3 = w3 + (size_t)e * II * HH;

    __shared__ short sA[2][128 * 32];
    __shared__ float sB1[2][64 * 32];
    __shared__ float sB2[2][64 * 32];
    __shared__ int s_tok[128];

    const int tid = threadIdx.x;
    if (tid < 128) s_tok[tid] = (m0 + tid < Me) ? lst[e * TT + m0 + tid] : 0;
    __syncthreads();

    const int lane = tid & 63, w = tid >> 6;
    const int wr = w >> 1, wc = w & 1;

    const short* srcA[2]; const float* srcB1[2]; const float* srcB3[2];
#pragma unroll
    for (int i = 0; i < 2; i++) {
        int Ra = (w * 2 + i) * 16 + (lane >> 2);
        srcA[i] = t16 + (size_t)(s_tok[Ra] >> 2) * HH + ((lane & 3) ^ (Ra & 3)) * 8;
        int Rb = (w * 2 + i) * 8 + (lane >> 3);
        size_t ro = (size_t)(n0 + Rb) * HH + ((lane & 7) ^ (Rb & 7)) * 4;
        srcB1[i] = we1 + ro;
        srcB3[i] = we3 + ro;
    }

    f4 acc1[4][2], acc2[4][2];
    const f4 zero = {0.f, 0.f, 0.f, 0.f};
#pragma unroll
    for (int i = 0; i < 4; i++)
#pragma unroll
        for (int j = 0; j < 2; j++) { acc1[i][j] = zero; acc2[i][j] = zero; }

#define DMA_TILE(db, kt)                                                       \
    {                                                                          \
        _Pragma("unroll")                                                      \
        for (int i = 0; i < 2; i++)                                            \
            g2l16(srcA[i] + (kt) * 32, (char*)sA[db] + (w * 2 + i) * 1024);    \
        _Pragma("unroll")                                                      \
        for (int i = 0; i < 2; i++)                                            \
            g2l16(srcB1[i] + (kt) * 32, (char*)sB1[db] + (w * 2 + i) * 1024);  \
        _Pragma("unroll")                                                      \
        for (int i = 0; i < 2; i++)                                            \
            g2l16(srcB3[i] + (kt) * 32, (char*)sB2[db] + (w * 2 + i) * 1024);  \
    }

    DMA_TILE(0, 0);
    const int nkt = HH / 32;   // 64
    for (int kt = 0; kt < nkt; ++kt) {
        const int db = kt & 1;
        if (kt + 1 < nkt) {
            DMA_TILE(db ^ 1, kt + 1);
            asm volatile("s_waitcnt vmcnt(6)" ::: "memory");  // tile kt landed
        } else {
            asm volatile("s_waitcnt vmcnt(0)" ::: "memory");
        }
        __builtin_amdgcn_s_barrier();
        asm volatile("" ::: "memory");

        s8 af[4];
#pragma unroll
        for (int mf = 0; mf < 4; mf++) {
            int r = wr * 64 + mf * 16 + (lane & 15);
            int byte = r * 64 + ((((lane >> 4) << 4)) ^ ((r & 3) << 4));
            af[mf] = *(const s8*)((const char*)sA[db] + byte);
        }
        s8 b1v[2], b2v[2];
#pragma unroll
        for (int nf = 0; nf < 2; nf++) {
            int r = wc * 32 + nf * 16 + (lane & 15);
            int base = r * 128;
            int o0 = ((lane >> 4) * 32) ^ ((r & 7) << 4);
            int o1 = ((lane >> 4) * 32 + 16) ^ ((r & 7) << 4);
            f4 x0 = *(const f4*)((const char*)sB1[db] + base + o0);
            f4 x1 = *(const f4*)((const char*)sB1[db] + base + o1);
            f4 y0 = *(const f4*)((const char*)sB2[db] + base + o0);
            f4 y1 = *(const f4*)((const char*)sB2[db] + base + o1);
            s8 bv1, bv2;
#pragma unroll
            for (int i = 0; i < 4; i++) {
                bv1[i] = f2bf(x0[i]); bv1[4 + i] = f2bf(x1[i]);
                bv2[i] = f2bf(y0[i]); bv2[4 + i] = f2bf(y1[i]);
            }
            b1v[nf] = bv1; b2v[nf] = bv2;
        }
        __builtin_amdgcn_s_setprio(1);
#pragma unroll
        for (int mf = 0; mf < 4; mf++)
#pragma unroll
            for (int nf = 0; nf < 2; nf++) {
                acc1[mf][nf] = __builtin_amdgcn_mfma_f32_16x16x32_bf16(
                    af[mf], b1v[nf], acc1[mf][nf], 0, 0, 0);
                acc2[mf][nf] = __builtin_amdgcn_mfma_f32_16x16x32_bf16(
                    af[mf], b2v[nf], acc2[mf][nf], 0, 0, 0);
            }
        __builtin_amdgcn_s_setprio(0);

        asm volatile("" ::: "memory");
        __builtin_amdgcn_s_barrier();   // all reads done -> next DMA may write
        asm volatile("" ::: "memory");
    }
#undef DMA_TILE

#pragma unroll
    for (int mf = 0; mf < 4; mf++) {
#pragma unroll
        for (int j = 0; j < 4; j++) {
            int rl = wr * 64 + mf * 16 + ((lane >> 4) << 2) + j;
            if (m0 + rl < Me) {
                size_t orow = (size_t)s_tok[rl] * II;
#pragma unroll
                for (int nf = 0; nf < 2; nf++) {
                    int ncol = n0 + wc * 32 + nf * 16 + (lane & 15);
                    float g = acc1[mf][nf][j];
                    float u = acc2[mf][nf][j];
                    float sg = g / (1.f + expf(-g));
                    h[orow + ncol] = f2bf(sg * u);
                }
            }
        }
    }
}

// ---------------------------------------------------------------------------
// Down GEMM, same all-DMA ping-pong structure. Tile 128x64, BK=32.
// LDS: A bf16 [2][128x32] + B fp32 [2][64x32] = 33K -> 4 blocks/CU.
// ---------------------------------------------------------------------------
__global__ __launch_bounds__(256, 4) void k_down(
        const short* __restrict__ h, const float* __restrict__ w2,
        short* __restrict__ buf2, const int* __restrict__ cnt,
        const int* __restrict__ lst, const float* __restrict__ lwt) {
    const int e = blockIdx.z;
    const int Me = cnt[e];
    const int m0 = blockIdx.y * 128;
    if (m0 >= Me) return;
    const int n0 = blockIdx.x * 64;
    const float* we = w2 + (size_t)e * HH * II;

    __shared__ short sA[2][128 * 32];
    __shared__ float sB[2][64 * 32];
    __shared__ int s_tok[128];
    __shared__ float s_wgt[128];

    const int tid = threadIdx.x;
    if (tid < 128) {
        bool v = (m0 + tid < Me);
        s_tok[tid] = v ? lst[e * TT + m0 + tid] : 0;
        s_wgt[tid] = v ? lwt[e * TT + m0 + tid] : 0.f;
    }
    __syncthreads();

    const int lane = tid & 63, w = tid >> 6;
    const int wr = w >> 1, wc = w & 1;

    const short* srcA[2]; const float* srcB[2];
#pragma unroll
    for (int i = 0; i < 2; i++) {
        int Ra = (w * 2 + i) * 16 + (lane >> 2);
        srcA[i] = h + (size_t)s_tok[Ra] * II + ((lane & 3) ^ (Ra & 3)) * 8;
        int Rb = (w * 2 + i) * 8 + (lane >> 3);
        srcB[i] = we + (size_t)(n0 + Rb) * II + ((lane & 7) ^ (Rb & 7)) * 4;
    }

    f4 acc[4][2];
    const f4 zero = {0.f, 0.f, 0.f, 0.f};
#pragma unroll
    for (int i = 0; i < 4; i++)
#pragma unroll
        for (int j = 0; j < 2; j++) acc[i][j] = zero;

#define DMA_TILE(db, kt)                                                       \
    {                                                                          \
        _Pragma("unroll")                                                      \
        for (int i = 0; i < 2; i++)                                            \
            g2l16(srcA[i] + (kt) * 32, (char*)sA[db] + (w * 2 + i) * 1024);    \
        _Pragma("unroll")                                                      \
        for (int i = 0; i < 2; i++)                                            \
            g2l16(srcB[i] + (kt) * 32, (char*)sB[db] + (w * 2 + i) * 1024);    \
    }

    DMA_TILE(0, 0);
    const int nkt = II / 32;   // 64
    for (int kt = 0; kt < nkt; ++kt) {
        const int db = kt & 1;
        if (kt + 1 < nkt) {
            DMA_TILE(db ^ 1, kt + 1);
            asm volatile("s_waitcnt vmcnt(4)" ::: "memory");
        } else {
            asm volatile("s_waitcnt vmcnt(0)" ::: "memory");
        }
        __builtin_amdgcn_s_barrier();
        asm volatile("" ::: "memory");

        s8 af[4];
#pragma unroll
        for (int mf = 0; mf < 4; mf++) {
            int r = wr * 64 + mf * 16 + (lane & 15);
            int byte = r * 64 + ((((lane >> 4) << 4)) ^ ((r & 3) << 4));
            af[mf] = *(const s8*)((const char*)sA[db] + byte);
        }
        s8 bv[2];
#pragma unroll
        for (int nf = 0; nf < 2; nf++) {
            int r = wc * 32 + nf * 16 + (lane & 15);
            int base = r * 128;
            int o0 = ((lane >> 4) * 32) ^ ((r & 7) << 4);
            int o1 = ((lane >> 4) * 32 + 16) ^ ((r & 7) << 4);
            f4 x0 = *(const f4*)((const char*)sB[db] + base + o0);
            f4 x1 = *(const f4*)((const char*)sB[db] + base + o1);
            s8 b;
#pragma unroll
            for (int i = 0; i < 4; i++) { b[i] = f2bf(x0[i]); b[4 + i] = f2bf(x1[i]); }
            bv[nf] = b;
        }
        __builtin_amdgcn_s_setprio(1);
#pragma unroll
        for (int mf = 0; mf < 4; mf++)
#pragma unroll
            for (int nf = 0; nf < 2; nf++)
                acc[mf][nf] = __builtin_amdgcn_mfma_f32_16x16x32_bf16(
                    af[mf], bv[nf], acc[mf][nf], 0, 0, 0);
        __builtin_amdgcn_s_setprio(0);

        asm volatile("" ::: "memory");
        __builtin_amdgcn_s_barrier();
        asm volatile("" ::: "memory");
    }
#undef DMA_TILE

#pragma unroll
    for (int mf = 0; mf < 4; mf++) {
#pragma unroll
        for (int j = 0; j < 4; j++) {
            int rl = wr * 64 + mf * 16 + ((lane >> 4) << 2) + j;
            if (m0 + rl < Me) {
                size_t orow = (size_t)s_tok[rl] * HH;
                float wgt = s_wgt[rl];
#pragma unroll
                for (int nf = 0; nf < 2; nf++) {
                    int ncol = n0 + wc * 32 + nf * 16 + (lane & 15);
                    buf2[orow + ncol] = f2bf(acc[mf][nf][j] * wgt);
                }
            }
        }
    }
}

// ---------------------------------------------------------------------------
// Final: out = x + sum_k buf2[token*4+k]  (buf2 bf16)
// ---------------------------------------------------------------------------
__global__ void k_final(const float* __restrict__ x, const short* __restrict__ buf2,
                        float* __restrict__ out) {
    size_t i8 = (size_t)blockIdx.x * 256 + threadIdx.x;
    size_t tok = i8 / (HH / 8);
    size_t c8 = i8 % (HH / 8);
    const f4* xp = (const f4*)x + i8 * 2;
    f4 r0 = xp[0], r1 = xp[1];
#pragma unroll
    for (int k = 0; k < KTOP; k++) {
        s8 b = ((const s8*)buf2)[(tok * KTOP + k) * (HH / 8) + c8];
#pragma unroll
        for (int j = 0; j < 4; j++) { r0[j] += bf2f(b[j]); r1[j] += bf2f(b[4 + j]); }
    }
    ((f4*)out)[i8 * 2] = r0;
    ((f4*)out)[i8 * 2 + 1] = r1;
}

// ---------------------------------------------------------------------------
extern "C" void kernel_launch(void* const* d_in, const int* in_sizes, int n_in,
                              void* d_out, int out_size, void* d_ws, size_t ws_size,
                              hipStream_t stream) {
    const float* x     = (const float*)d_in[0];
    const float* gamma = (const float*)d_in[1];
    const float* wg    = (const float*)d_in[2];
    const float* bg    = (const float*)d_in[3];
    const float* w1    = (const float*)d_in[4];
    const float* w3    = (const float*)d_in[5];
    const float* w2    = (const float*)d_in[6];
    float* out = (float*)d_out;

    char* ws = (char*)d_ws;
    size_t off = 0;
    short* t16  = (short*)(ws + off); off += (size_t)TT * HH * 2;          // 16 MB
    short* h1   = (short*)(ws + off); off += (size_t)TT * KTOP * II * 2;   // 64 MB
    short* buf2 = (short*)(ws + off); off += (size_t)TT * KTOP * HH * 2;   // 64 MB
    int* cnt    = (int*)(ws + off); off += 256;
    int* lst    = (int*)(ws + off); off += (size_t)EE * TT * 4;
    float* lwt  = (float*)(ws + off); off += (size_t)EE * TT * 4;

    hipMemsetAsync(cnt, 0, EE * sizeof(int), stream);
    k_router<<<TT / 4, 256, 0, stream>>>(x, gamma, wg, bg, t16, cnt, lst, lwt);

    dim3 g1(II / 64, TT / 128, EE);    // 32 x 32 x 16
    k_ffn<<<g1, 256, 0, stream>>>(t16, w1, w3, h1, cnt, lst);

    dim3 g2(HH / 64, TT / 128, EE);
    k_down<<<g2, 256, 0, stream>>>(h1, w2, buf2, cnt, lst, lwt);

    k_final<<<(TT * HH / 8) / 256, 256, 0, stream>>>(x, buf2, out);
}

// Round 13
// 905.849 us; speedup vs baseline: 1.1410x; 1.1410x over previous
//
#include <hip/hip_runtime.h>
#include <hip/hip_bf16.h>

constexpr int TT = 4096;   // tokens
constexpr int HH = 2048;   // hidden
constexpr int II = 2048;   // intermediate
constexpr int EE = 16;     // experts
constexpr int KTOP = 4;    // top-k

typedef __attribute__((ext_vector_type(4))) float f4;
typedef __attribute__((ext_vector_type(8))) short s8;
typedef __attribute__((ext_vector_type(4))) short sh4;

__device__ __forceinline__ short f2bf(float f) {
    union { __hip_bfloat16 b; short s; } u;
    u.b = __float2bfloat16(f);
    return u.s;
}
__device__ __forceinline__ float bf2f(short s) {
    union { unsigned u; float f; } v;
    v.u = ((unsigned)(unsigned short)s) << 16;
    return v.f;
}

// ---------------------------------------------------------------------------
// Router + RMSNorm, wave-parallel over experts: one block per token, 4 waves;
// wave w computes logits for experts w*4..w*4+3 (4x less serial reduce depth
// than the 16-sequential version). Wave 0 writes t16. fp32 throughout.
// ---------------------------------------------------------------------------
__global__ void k_router(const float* __restrict__ x, const float* __restrict__ gamma,
                         const float* __restrict__ wg, const float* __restrict__ bg,
                         short* __restrict__ t16, int* __restrict__ cnt,
                         int* __restrict__ lst, float* __restrict__ lwt) {
    const int tok = blockIdx.x;
    const int lane = threadIdx.x & 63;
    const int w = threadIdx.x >> 6;

    const f4* xr = (const f4*)(x + (size_t)tok * HH);
    const f4* gr = (const f4*)gamma;

    f4 t4[8];
    float ss = 0.f;
#pragma unroll
    for (int j = 0; j < 8; j++) {
        f4 v = xr[lane + 64 * j];
        t4[j] = v;
        ss += v[0] * v[0] + v[1] * v[1] + v[2] * v[2] + v[3] * v[3];
    }
#pragma unroll
    for (int m = 32; m >= 1; m >>= 1) ss += __shfl_xor(ss, m);
    const float rs = rsqrtf(ss * (1.f / HH) + 1e-6f);
#pragma unroll
    for (int j = 0; j < 8; j++) {
        f4 g = gr[lane + 64 * j];
#pragma unroll
        for (int i = 0; i < 4; i++) t4[j][i] *= rs * g[i];
    }

    // wave 0 writes the normalized row (all waves computed identical values)
    if (w == 0) {
        short* tr = t16 + (size_t)tok * HH;
#pragma unroll
        for (int j = 0; j < 8; j++) {
            sh4 o;
#pragma unroll
            for (int i = 0; i < 4; i++) o[i] = f2bf(t4[j][i]);
            *(sh4*)(tr + (size_t)(lane + 64 * j) * 4) = o;
        }
    }

    __shared__ float sh_logit[EE];
#pragma unroll
    for (int q = 0; q < 4; q++) {
        const int e = w * 4 + q;
        const f4* wrow = (const f4*)(wg + (size_t)e * HH);
        float a = 0.f;
#pragma unroll
        for (int j = 0; j < 8; j++) {
            f4 wv = wrow[lane + 64 * j];
            a += t4[j][0] * wv[0] + t4[j][1] * wv[1] + t4[j][2] * wv[2] + t4[j][3] * wv[3];
        }
#pragma unroll
        for (int m = 32; m >= 1; m >>= 1) a += __shfl_xor(a, m);
        if (lane == 0) sh_logit[e] = a + bg[e];
    }
    __syncthreads();

    if (threadIdx.x == 0) {
        float logit[EE];
#pragma unroll
        for (int e = 0; e < EE; e++) logit[e] = sh_logit[e];
        unsigned chosen = 0u;
        int sel[KTOP]; float sv[KTOP];
#pragma unroll
        for (int k = 0; k < KTOP; k++) {
            float best = -1e30f; int bi = 0;
#pragma unroll
            for (int e = 0; e < EE; e++) {
                bool take = (!((chosen >> e) & 1u)) && (logit[e] > best);
                if (take) { best = logit[e]; bi = e; }
            }
            chosen |= 1u << bi; sel[k] = bi; sv[k] = best;
        }
        const float lmax = sv[0];
        float s = 0.f;
#pragma unroll
        for (int k = 0; k < KTOP; k++) { sv[k] = expf(sv[k] - lmax); s += sv[k]; }
        const float inv = 1.f / s;
#pragma unroll
        for (int k = 0; k < KTOP; k++) {
            int e = sel[k];
            int p = atomicAdd(&cnt[e], 1);
            lst[e * TT + p] = tok * KTOP + k;
            lwt[e * TT + p] = sv[k] * inv;
        }
    }
}

// ---------------------------------------------------------------------------
// FUSED gate+up grouped GEMM: h[pk] = silu(t@w1e^T) * (t@w3e^T).
// 128x128 tile, BK=64, 4 waves, XOR-swizzled LDS. (round-7/9-proven)
// ---------------------------------------------------------------------------
__global__ __launch_bounds__(256, 2) void k_gemm_ffn_fused(
        const short* __restrict__ t16, const float* __restrict__ w1,
        const float* __restrict__ w3, short* __restrict__ h,
        const int* __restrict__ cnt, const int* __restrict__ lst) {
    const int e = blockIdx.z;
    const int Me = cnt[e];
    const int m0 = blockIdx.y * 128;
    if (m0 >= Me) return;
    const int n0 = blockIdx.x * 128;
    const float* we1 = w1 + (size_t)e * II * HH;   // [N=I][K=H] row-major
    const float* we3 = w3 + (size_t)e * II * HH;

    __shared__ char lA[16384];
    __shared__ char lB1[16384];
    __shared__ char lB2[16384];
    __shared__ int s_tok[128];

    const int tid = threadIdx.x;
    if (tid < 128) s_tok[tid] = (m0 + tid < Me) ? lst[e * TT + m0 + tid] : 0;
    __syncthreads();

    const int lane = tid & 63, wid = tid >> 6;
    const int wr = wid >> 1, wc = wid & 1;

    f4 acc1[4][4], acc2[4][4];
    const f4 zero = {0.f, 0.f, 0.f, 0.f};
#pragma unroll
    for (int i = 0; i < 4; i++)
#pragma unroll
        for (int j = 0; j < 4; j++) { acc1[i][j] = zero; acc2[i][j] = zero; }

    const int rbase = tid >> 3;
    const int kc = (tid & 7) * 8;
    const int lb0 = rbase * 128 + ((kc * 2) ^ ((rbase & 7) << 4));
    int tokrow[4];
#pragma unroll
    for (int j = 0; j < 4; j++) tokrow[j] = s_tok[rbase + 32 * j] >> 2;

    for (int kt = 0; kt < HH / 64; ++kt) {
        __syncthreads();
#pragma unroll
        for (int j = 0; j < 4; j++) {
            s8 av = *(const s8*)(t16 + (size_t)tokrow[j] * HH + kt * 64 + kc);
            *(s8*)(lA + lb0 + 4096 * j) = av;
        }
#pragma unroll
        for (int j = 0; j < 4; j++) {
            size_t roff = (size_t)(n0 + rbase + 32 * j) * HH + kt * 64 + kc;
            {
                f4 b0 = *(const f4*)(we1 + roff);
                f4 b1 = *(const f4*)(we1 + roff + 4);
                s8 bv;
#pragma unroll
                for (int i = 0; i < 4; i++) { bv[i] = f2bf(b0[i]); bv[4 + i] = f2bf(b1[i]); }
                *(s8*)(lB1 + lb0 + 4096 * j) = bv;
            }
            {
                f4 b0 = *(const f4*)(we3 + roff);
                f4 b1 = *(const f4*)(we3 + roff + 4);
                s8 bv;
#pragma unroll
                for (int i = 0; i < 4; i++) { bv[i] = f2bf(b0[i]); bv[4 + i] = f2bf(b1[i]); }
                *(s8*)(lB2 + lb0 + 4096 * j) = bv;
            }
        }
        __syncthreads();
#pragma unroll
        for (int kk = 0; kk < 2; ++kk) {
            s8 af[4], b1v[4], b2v[4];
#pragma unroll
            for (int mf = 0; mf < 4; mf++) {
                int r = wr * 64 + mf * 16 + (lane & 15);
                int byte = r * 128 + (((kk * 64) + ((lane >> 4) << 4)) ^ ((r & 7) << 4));
                af[mf] = *(const s8*)(lA + byte);
            }
#pragma unroll
            for (int nf = 0; nf < 4; nf++) {
                int r = wc * 64 + nf * 16 + (lane & 15);
                int byte = r * 128 + (((kk * 64) + ((lane >> 4) << 4)) ^ ((r & 7) << 4));
                b1v[nf] = *(const s8*)(lB1 + byte);
                b2v[nf] = *(const s8*)(lB2 + byte);
            }
#pragma unroll
            for (int mf = 0; mf < 4; mf++)
#pragma unroll
                for (int nf = 0; nf < 4; nf++) {
                    acc1[mf][nf] = __builtin_amdgcn_mfma_f32_16x16x32_bf16(
                        af[mf], b1v[nf], acc1[mf][nf], 0, 0, 0);
                    acc2[mf][nf] = __builtin_amdgcn_mfma_f32_16x16x32_bf16(
                        af[mf], b2v[nf], acc2[mf][nf], 0, 0, 0);
                }
        }
    }
#pragma unroll
    for (int mf = 0; mf < 4; mf++) {
#pragma unroll
        for (int j = 0; j < 4; j++) {
            int rl = wr * 64 + mf * 16 + ((lane >> 4) << 2) + j;
            if (m0 + rl < Me) {
                size_t orow = (size_t)s_tok[rl] * II;
#pragma unroll
                for (int nf = 0; nf < 4; nf++) {
                    int ncol = n0 + wc * 64 + nf * 16 + (lane & 15);
                    float g = acc1[mf][nf][j];
                    float u = acc2[mf][nf][j];
                    float sg = g / (1.f + expf(-g));
                    h[orow + ncol] = f2bf(sg * u);
                }
            }
        }
    }
}

// ---------------------------------------------------------------------------
// Grouped GEMM (down), round-9-proven: raw barriers (lgkm-only waits) +
// register prefetch of tile kt+1 issued before the compute barrier.
// ---------------------------------------------------------------------------
__global__ __launch_bounds__(256, 2) void k_gemm_down(
        const short* __restrict__ h, const float* __restrict__ w2,
        short* __restrict__ buf2, const int* __restrict__ cnt,
        const int* __restrict__ lst, const float* __restrict__ lwt) {
    const int e = blockIdx.z;
    const int Me = cnt[e];
    const int m0 = blockIdx.y * 128;
    if (m0 >= Me) return;
    const int n0 = blockIdx.x * 128;
    const float* we = w2 + (size_t)e * HH * II;  // [N=H][K=I] row-major

    __shared__ char lA[16384];
    __shared__ char lB[16384];
    __shared__ int s_tok[128];
    __shared__ float s_wgt[128];

    const int tid = threadIdx.x;
    if (tid < 128) {
        bool v = (m0 + tid < Me);
        s_tok[tid] = v ? lst[e * TT + m0 + tid] : 0;
        s_wgt[tid] = v ? lwt[e * TT + m0 + tid] : 0.f;
    }
    __syncthreads();

    const int lane = tid & 63, wid = tid >> 6;
    const int wr = wid >> 1, wc = wid & 1;

    f4 acc[4][4];
    const f4 zero = {0.f, 0.f, 0.f, 0.f};
#pragma unroll
    for (int i = 0; i < 4; i++)
#pragma unroll
        for (int j = 0; j < 4; j++) acc[i][j] = zero;

    const int rbase = tid >> 3;
    const int kc = (tid & 7) * 8;
    const int lb0 = rbase * 128 + ((kc * 2) ^ ((rbase & 7) << 4));
    const short* gA[4]; const float* gB[4];
#pragma unroll
    for (int j = 0; j < 4; j++) {
        gA[j] = h + (size_t)s_tok[rbase + 32 * j] * II + kc;
        gB[j] = we + (size_t)(n0 + rbase + 32 * j) * II + kc;
    }

    s8 ar[4]; f4 br[4][2];
#define PREFETCH(kt)                                                           \
    _Pragma("unroll")                                                          \
    for (int j = 0; j < 4; j++) {                                              \
        ar[j] = *(const s8*)(gA[j] + (kt) * 64);                               \
        br[j][0] = *(const f4*)(gB[j] + (kt) * 64);                            \
        br[j][1] = *(const f4*)(gB[j] + (kt) * 64 + 4);                        \
    }

    PREFETCH(0);
    const int nkt = II / 64;
    for (int kt = 0; kt < nkt; ++kt) {
        asm volatile("" ::: "memory");
        __builtin_amdgcn_s_barrier();
        asm volatile("" ::: "memory");
#pragma unroll
        for (int j = 0; j < 4; j++) {
            *(s8*)(lA + lb0 + 4096 * j) = ar[j];
            s8 bv;
#pragma unroll
            for (int i = 0; i < 4; i++) { bv[i] = f2bf(br[j][0][i]); bv[4 + i] = f2bf(br[j][1][i]); }
            *(s8*)(lB + lb0 + 4096 * j) = bv;
        }
        if (kt + 1 < nkt) PREFETCH(kt + 1);
        asm volatile("s_waitcnt lgkmcnt(0)" ::: "memory");
        __builtin_amdgcn_s_barrier();
        asm volatile("" ::: "memory");
#pragma unroll
        for (int kk = 0; kk < 2; ++kk) {
            s8 af[4], bfr[4];
#pragma unroll
            for (int mf = 0; mf < 4; mf++) {
                int r = wr * 64 + mf * 16 + (lane & 15);
                int byte = r * 128 + (((kk * 64) + ((lane >> 4) << 4)) ^ ((r & 7) << 4));
                af[mf] = *(const s8*)(lA + byte);
            }
#pragma unroll
            for (int nf = 0; nf < 4; nf++) {
                int r = wc * 64 + nf * 16 + (lane & 15);
                int byte = r * 128 + (((kk * 64) + ((lane >> 4) << 4)) ^ ((r & 7) << 4));
                bfr[nf] = *(const s8*)(lB + byte);
            }
#pragma unroll
            for (int mf = 0; mf < 4; mf++)
#pragma unroll
                for (int nf = 0; nf < 4; nf++)
                    acc[mf][nf] = __builtin_amdgcn_mfma_f32_16x16x32_bf16(
                        af[mf], bfr[nf], acc[mf][nf], 0, 0, 0);
        }
    }
#undef PREFETCH
#pragma unroll
    for (int mf = 0; mf < 4; mf++) {
#pragma unroll
        for (int j = 0; j < 4; j++) {
            int rl = wr * 64 + mf * 16 + ((lane >> 4) << 2) + j;
            if (m0 + rl < Me) {
                size_t orow = (size_t)s_tok[rl] * HH;
                float wgt = s_wgt[rl];
#pragma unroll
                for (int nf = 0; nf < 4; nf++) {
                    int ncol = n0 + wc * 64 + nf * 16 + (lane & 15);
                    buf2[orow + ncol] = f2bf(acc[mf][nf][j] * wgt);
                }
            }
        }
    }
}

// ---------------------------------------------------------------------------
// Final: out = x + sum_k buf2[token*4+k]  (buf2 bf16)
// ---------------------------------------------------------------------------
__global__ void k_final(const float* __restrict__ x, const short* __restrict__ buf2,
                        float* __restrict__ out) {
    size_t i8 = (size_t)blockIdx.x * 256 + threadIdx.x;  // 8-elem chunk
    size_t tok = i8 / (HH / 8);
    size_t c8 = i8 % (HH / 8);
    const f4* xp = (const f4*)x + i8 * 2;
    f4 r0 = xp[0], r1 = xp[1];
#pragma unroll
    for (int k = 0; k < KTOP; k++) {
        s8 b = ((const s8*)buf2)[(tok * KTOP + k) * (HH / 8) + c8];
#pragma unroll
        for (int j = 0; j < 4; j++) { r0[j] += bf2f(b[j]); r1[j] += bf2f(b[4 + j]); }
    }
    ((f4*)out)[i8 * 2] = r0;
    ((f4*)out)[i8 * 2 + 1] = r1;
}

// ---------------------------------------------------------------------------
extern "C" void kernel_launch(void* const* d_in, const int* in_sizes, int n_in,
                              void* d_out, int out_size, void* d_ws, size_t ws_size,
                              hipStream_t stream) {
    const float* x     = (const float*)d_in[0];
    const float* gamma = (const float*)d_in[1];
    const float* wg    = (const float*)d_in[2];
    const float* bg    = (const float*)d_in[3];
    const float* w1    = (const float*)d_in[4];
    const float* w3    = (const float*)d_in[5];
    const float* w2    = (const float*)d_in[6];
    float* out = (float*)d_out;

    char* ws = (char*)d_ws;
    size_t off = 0;
    short* t16  = (short*)(ws + off); off += (size_t)TT * HH * 2;          // 16 MB
    short* h1   = (short*)(ws + off); off += (size_t)TT * KTOP * II * 2;   // 64 MB
    short* buf2 = (short*)(ws + off); off += (size_t)TT * KTOP * HH * 2;   // 64 MB
    int* cnt    = (int*)(ws + off); off += 256;
    int* lst    = (int*)(ws + off); off += (size_t)EE * TT * 4;
    float* lwt  = (float*)(ws + off); off += (size_t)EE * TT * 4;

    hipMemsetAsync(cnt, 0, EE * sizeof(int), stream);
    k_router<<<TT, 256, 0, stream>>>(x, gamma, wg, bg, t16, cnt, lst, lwt);

    dim3 g1(II / 128, TT / 128, EE);
    k_gemm_ffn_fused<<<g1, 256, 0, stream>>>(t16, w1, w3, h1, cnt, lst);

    dim3 g2(HH / 128, TT / 128, EE);
    k_gemm_down<<<g2, 256, 0, stream>>>(h1, w2, buf2, cnt, lst, lwt);

    k_final<<<(TT * HH / 8) / 256, 256, 0, stream>>>(x, buf2, out);
}